// Round 8
// baseline (3897.666 us; speedup 1.0000x reference)
//
#include <hip/hip_runtime.h>

typedef __attribute__((ext_vector_type(8))) short s16x8;
typedef __attribute__((ext_vector_type(4))) float f32x4;
typedef __attribute__((ext_vector_type(16))) float f32x16;

#define BATCH 32768
#define LSEQ 128
// 32x32 A-frag store: [8 triples][4 gates(r,z,hn,in)][17 ks][512 shorts]
#define W32_SHORTS (8 * 4 * 17 * 512)                 // 278528
#define WFC_SHORTS 4096
#define XT_OFF_BYTES ((W32_SHORTS + WFC_SHORTS) * 2)  // 565248
#define WS_NEED_XT (XT_OFF_BYTES + BATCH * LSEQ * 4)  // ~17.3 MB

#define HROW 264                       // padded h row stride (shorts)
#define HBUF_S (128 * HROW)            // 33792 shorts = 67584 B per buffer
#define LDS_BYTES (2 * HBUF_S * 2)     // 135168 B

#define L2E 1.4426950408889634f
#define LN2 0.6931471805599453f

#define MFMA32(A, B, C) __builtin_amdgcn_mfma_f32_32x32x16_bf16(A, B, C, 0, 0, 0)
#define MFMA16(A, B, C) __builtin_amdgcn_mfma_f32_16x16x32_bf16(A, B, C, 0, 0, 0)

__device__ __forceinline__ unsigned short f2b(float f) {
  unsigned u = __float_as_uint(f);
  u += 0x7FFFu + ((u >> 16) & 1u);     // RNE bf16
  return (unsigned short)(u >> 16);
}

__device__ __forceinline__ float exp2n(float x) { float r; asm("v_exp_f32 %0, -%1" : "=v"(r) : "v"(x)); return r; }
__device__ __forceinline__ float exp2p(float x) { float r; asm("v_exp_f32 %0, %1" : "=v"(r) : "v"(x)); return r; }
__device__ __forceinline__ float rcp_(float x)  { float r; asm("v_rcp_f32 %0, %1" : "=v"(r) : "v"(x)); return r; }
__device__ __forceinline__ float log2_(float x) { float r; asm("v_log_f32 %0, %1" : "=v"(r) : "v"(x)); return r; }
__device__ __forceinline__ unsigned cvtpk(float lo, float hi) {
  unsigned r; asm("v_cvt_pk_bf16_f32 %0, %1, %2" : "=v"(r) : "v"(lo), "v"(hi)); return r;
}

// Pack weights into 32x32x16 MFMA A-fragment order (unfolded, no L2E):
// frag(tr, g, ks): A-row j = g*256 + tr*32 + (lane&31)  [g=3 unused by main]
// k = ks*16 + (lane>>5)*8 + e (ks<16); ks==16 aug tile: k256=x coeff, k257=bias.
__global__ void gru_prep(const float* __restrict__ Wih, const float* __restrict__ Whh,
                         const float* __restrict__ bih, const float* __restrict__ bhh,
                         const float* __restrict__ Wfc,
                         unsigned short* __restrict__ wfrag,
                         unsigned short* __restrict__ wfc16) {
  int t = blockIdx.x * 256 + threadIdx.x;
  if (t < W32_SHORTS) {
    int e = t & 7, lane = (t >> 3) & 63, frag = t >> 9;
    int ks = frag % 17, g = (frag / 17) & 3, tr = frag / 68;
    int l31 = lane & 31, hh = lane >> 5;
    int k = (ks < 16) ? ks * 16 + hh * 8 + e : 256 + hh * 8 + e;
    float val = 0.f;
    if (g < 3) {
      int j = g * 256 + tr * 32 + l31;
      if (k < 256) val = Whh[j * 256 + k];
      else if (k == 256) val = (g < 2) ? Wih[j] : 0.f;
      else if (k == 257) val = (g < 2) ? (bih[j] + bhh[j]) : bhh[j];
    }
    wfrag[t] = f2b(val);
  } else if (t < W32_SHORTS + WFC_SHORTS) {   // W_fc bf16 [16][256] row-major
    int t2 = t - W32_SHORTS;
    wfc16[t2] = f2b(Wfc[t2]);
  }
}

__global__ void x_transpose(const int* __restrict__ x, int* __restrict__ xT) {
  __shared__ int tile[32][33];
  int l0 = blockIdx.x * 32, b0 = blockIdx.y * 32;
  for (int r = threadIdx.y; r < 32; r += 8)
    tile[r][threadIdx.x] = x[(b0 + r) * LSEQ + l0 + threadIdx.x];
  __syncthreads();
  for (int r = threadIdx.y; r < 32; r += 8)
    xT[(l0 + r) * BATCH + b0 + threadIdx.x] = tile[threadIdx.x][r];
}

template <int XT>
__global__ __attribute__((amdgpu_waves_per_eu(2, 2))) __launch_bounds__(512)
void gru_main(const int* __restrict__ x, const int* __restrict__ xTr,
              const unsigned short* __restrict__ wfrag,
              const unsigned short* __restrict__ wfc16,
              const float* __restrict__ Wih, const float* __restrict__ bih,
              const float* __restrict__ bfc, float* __restrict__ out) {
  extern __shared__ unsigned short sm[];
  unsigned short* h0 = sm;
  unsigned short* h1 = sm + HBUF_S;

  const int tid = threadIdx.x;
  const int lane = tid & 63;
  const int wv = tid >> 6;       // wave 0..7 = j-triple index tr
  const int tr = wv;
  const int l31 = lane & 31;     // batch col within 32-group
  const int hh = lane >> 5;      // k-half
  const int q = lane >> 4;       // FC 16x16 coords
  const int b = lane & 15;
  const int bbase = blockIdx.x * 128;

  { // zero h0 (h1 fully written in step 0 before any read)
    unsigned int* p = (unsigned int*)h0;
#pragma unroll
    for (int r = 0; r < 33; ++r) p[tid + r * 512] = 0u;
  }

  // i_n coefficients for this wave's 16 C-rows, packed (bf16 w | bf16 b)
  unsigned winbin[16];
#pragma unroll
  for (int reg = 0; reg < 16; ++reg) {
    int crow = (reg & 3) + 8 * (reg >> 2) + 4 * hh;
    int j = 512 + tr * 32 + crow;
    winbin[reg] = (unsigned)f2b(Wih[j]) | ((unsigned)f2b(bih[j]) << 16);
  }
  float bfc4[4];
#pragma unroll
  for (int r = 0; r < 4; ++r) bfc4[r] = bfc[q * 4 + r];

  const f32x16 z16 = {0, 0, 0, 0, 0, 0, 0, 0, 0, 0, 0, 0, 0, 0, 0, 0};

  float lp = 0.f;
  __syncthreads();

#pragma unroll 1
  for (int i = 0; i < LSEQ; ++i) {
    const unsigned short* rdb = (i & 1) ? h1 : h0;   // h_{i-1}
    unsigned short* wrb = (i & 1) ? h0 : h1;         // h_i

    // launder pointers: keep per-step loads from being hoisted across steps
    unsigned long wfu = (unsigned long)wfrag;
    asm volatile("" : "+s"(wfu));
    const unsigned short* wfp = (const unsigned short*)wfu;
    unsigned long wcu = (unsigned long)wfc16;
    asm volatile("" : "+s"(wcu));
    const unsigned short* wc = (const unsigned short*)wcu;

    const unsigned short* fR = wfp + ((tr * 4 + 0) * 17) * 512 + lane * 8;
    const unsigned short* fZ = wfp + ((tr * 4 + 1) * 17) * 512 + lane * 8;
    const unsigned short* fH = wfp + ((tr * 4 + 2) * 17) * 512 + lane * 8;

    // x inputs (x_in = x[:, i-1], 0 at i==0); values 0..15 exact in bf16
    float xin4[4];
    unsigned xlo[4];
#pragma unroll
    for (int bg = 0; bg < 4; ++bg) {
      float xv;
      if (XT) xv = (i > 0) ? (float)xTr[(i - 1) * BATCH + bbase + bg * 32 + l31] : 0.f;
      else    xv = (i > 0) ? (float)x[(bbase + bg * 32 + l31) * LSEQ + i - 1] : 0.f;
      xin4[bg] = xv;
      xlo[bg] = (hh == 0) ? ((__float_as_uint(xv) >> 16) | 0x3F800000u) : 0u;
    }

    // ---- aug-first: initialize 12 accumulators with gi + bias (C = 0) ----
    s16x8 ar = *(const s16x8*)(fR + 16 * 512);
    s16x8 az = *(const s16x8*)(fZ + 16 * 512);
    s16x8 ah = *(const s16x8*)(fH + 16 * 512);
    f32x16 aRc[4], aZc[4], aHc[4];
#pragma unroll
    for (int bg = 0; bg < 4; ++bg) {
      union { unsigned u[4]; s16x8 v; } xf;
      xf.u[0] = xlo[bg]; xf.u[1] = xf.u[2] = xf.u[3] = 0u;
      aRc[bg] = MFMA32(ar, xf.v, z16);
      aZc[bg] = MFMA32(az, xf.v, z16);
      aHc[bg] = MFMA32(ah, xf.v, z16);
    }

    // per-bg LDS base pointers (B-frag: + ks*16 compile-time imm)
    const unsigned short* rb[4];
#pragma unroll
    for (int bg = 0; bg < 4; ++bg) rb[bg] = rdb + (bg * 32 + l31) * HROW + 8 * hh;

    // ---- K loop: weights read ONCE, h B-frags read ONCE per wave ----
    s16x8 cr = *(const s16x8*)(fR);
    s16x8 cz = *(const s16x8*)(fZ);
    s16x8 ch = *(const s16x8*)(fH);
#pragma unroll
    for (int ks = 0; ks < 16; ++ks) {
      s16x8 nr, nz, nh;
      if (ks < 15) {   // depth-1 prefetch
        nr = *(const s16x8*)(fR + (ks + 1) * 512);
        nz = *(const s16x8*)(fZ + (ks + 1) * 512);
        nh = *(const s16x8*)(fH + (ks + 1) * 512);
      }
#pragma unroll
      for (int bg = 0; bg < 4; ++bg) {
        const s16x8 hb = *(const s16x8*)&rb[bg][ks * 16];
        aRc[bg] = MFMA32(cr, hb, aRc[bg]);
        aZc[bg] = MFMA32(cz, hb, aZc[bg]);
        aHc[bg] = MFMA32(ch, hb, aHc[bg]);
      }
      if (ks < 15) { cr = nr; cz = nz; ch = nh; }
    }

    // ---- gate epilogue + direct h write ----
#pragma unroll
    for (int bg = 0; bg < 4; ++bg) {
      const float xv = xin4[bg];
      const int rowb = (bg * 32 + l31) * HROW;
#pragma unroll
      for (int rq = 0; rq < 4; ++rq) {
        const int col = tr * 32 + 4 * hh + 8 * rq;
        const uint2 hp = *(const uint2*)&rdb[rowb + col];
        const float hpv[4] = {
            __uint_as_float(hp.x << 16), __uint_as_float(hp.x & 0xFFFF0000u),
            __uint_as_float(hp.y << 16), __uint_as_float(hp.y & 0xFFFF0000u)};
        float hv[4];
#pragma unroll
        for (int e2 = 0; e2 < 4; ++e2) {
          const int idx = rq * 4 + e2;
          const unsigned u = winbin[idx];
          const float inr = fmaf(xv, __uint_as_float(u << 16),
                                 __uint_as_float(u & 0xFFFF0000u));
          float rr = rcp_(1.f + exp2n(L2E * aRc[bg][idx]));   // sigmoid
          float zz = rcp_(1.f + exp2n(L2E * aZc[bg][idx]));
          float y  = fmaf(rr, aHc[bg][idx], inr);             // i_n + r*h_n
          float uu = rcp_(1.f + exp2p((2.f * L2E) * y));
          float nn = fmaf(-2.f, uu, 1.f);                     // tanh
          hv[e2] = fmaf(zz, hpv[e2] - nn, nn);                // (1-z)*n + z*h
        }
        *(uint2*)&wrb[rowb + col] =
            make_uint2(cvtpk(hv[0], hv[1]), cvtpk(hv[2], hv[3]));
      }
    }

    __syncthreads();   // h_i fully visible; only barrier per step

    { // FC + log_softmax + gather; wave wv handles batch tile bt == wv
      const int lrow = wv * 16 + b;
      const int grow = bbase + lrow;
      f32x4 fa = {bfc4[0], bfc4[1], bfc4[2], bfc4[3]};
      const unsigned short* hbb = wrb + lrow * HROW + 8 * q;
      const unsigned short* wcb = wc + b * 256 + q * 8;
#pragma unroll
      for (int ks = 0; ks < 8; ++ks) {
        s16x8 wfcf = *(const s16x8*)(wcb + 32 * ks);
        s16x8 hb = *(const s16x8*)(hbb + 32 * ks);
        fa = MFMA16(wfcf, hb, fa);
      }
      int tgt = XT ? xTr[i * BATCH + grow] : x[grow * LSEQ + i];
      float l0 = fa[0], l1 = fa[1], l2 = fa[2], l3 = fa[3];
      float mx = fmaxf(fmaxf(l0, l1), fmaxf(l2, l3));
      mx = fmaxf(mx, __shfl_xor(mx, 16));
      mx = fmaxf(mx, __shfl_xor(mx, 32));
      float se = exp2p(L2E * (l0 - mx)) + exp2p(L2E * (l1 - mx)) +
                 exp2p(L2E * (l2 - mx)) + exp2p(L2E * (l3 - mx));
      se += __shfl_xor(se, 16);
      se += __shfl_xor(se, 32);
      float v01 = (tgt & 1) ? l1 : l0;
      float v23 = (tgt & 1) ? l3 : l2;
      float vs = (tgt & 2) ? v23 : v01;
      float contrib = (q == (tgt >> 2)) ? vs : 0.f;
      contrib += __shfl_xor(contrib, 16);
      contrib += __shfl_xor(contrib, 32);
      lp += contrib - mx - LN2 * log2_(se);
    }
  }

  if (q == 0) out[bbase + wv * 16 + b] = lp;
}

extern "C" void kernel_launch(void* const* d_in, const int* in_sizes, int n_in,
                              void* d_out, int out_size, void* d_ws, size_t ws_size,
                              hipStream_t stream) {
  (void)in_sizes; (void)n_in; (void)out_size;
  const int*   x   = (const int*)d_in[0];
  const float* Wih = (const float*)d_in[1];
  const float* Whh = (const float*)d_in[2];
  const float* bih = (const float*)d_in[3];
  const float* bhh = (const float*)d_in[4];
  const float* Wfc = (const float*)d_in[5];
  const float* bfc = (const float*)d_in[6];
  float* out = (float*)d_out;

  unsigned short* wfrag = (unsigned short*)d_ws;
  unsigned short* wfc16 = wfrag + W32_SHORTS;
  int* xT = (int*)((char*)d_ws + XT_OFF_BYTES);

  gru_prep<<<dim3((W32_SHORTS + WFC_SHORTS) / 256), dim3(256), 0, stream>>>(
      Wih, Whh, bih, bhh, Wfc, wfrag, wfc16);

  if (ws_size >= (size_t)WS_NEED_XT) {
    x_transpose<<<dim3(LSEQ / 32, BATCH / 32), dim3(32, 8), 0, stream>>>(x, xT);
    hipFuncSetAttribute((const void*)gru_main<1>,
                        hipFuncAttributeMaxDynamicSharedMemorySize, LDS_BYTES);
    gru_main<1><<<dim3(256), dim3(512), LDS_BYTES, stream>>>(x, xT, wfrag, wfc16,
                                                             Wih, bih, bfc, out);
  } else {
    hipFuncSetAttribute((const void*)gru_main<0>,
                        hipFuncAttributeMaxDynamicSharedMemorySize, LDS_BYTES);
    gru_main<0><<<dim3(256), dim3(512), LDS_BYTES, stream>>>(x, x, wfrag, wfc16,
                                                             Wih, bih, bfc, out);
  }
}

// Round 9
// 2187.065 us; speedup vs baseline: 1.7821x; 1.7821x over previous
//
#include <hip/hip_runtime.h>

typedef __attribute__((ext_vector_type(8))) short s16x8;
typedef __attribute__((ext_vector_type(4))) float f32x4;
typedef __attribute__((ext_vector_type(16))) float f32x16;

#define BATCH 32768
#define LSEQ 128
// 32x32 A-frag store: [8 triples][4 gates(r,z,hn,in)][17 ks][512 shorts]
#define W32_SHORTS (8 * 4 * 17 * 512)                 // 278528
#define WFC_SHORTS 4096
#define XT_OFF_BYTES ((W32_SHORTS + WFC_SHORTS) * 2)  // 565248
#define WS_NEED_XT (XT_OFF_BYTES + BATCH * LSEQ * 4)  // ~17.3 MB

#define HROW 264                       // padded h row stride (shorts)
#define HBUF_S (128 * HROW)            // 33792 shorts = 67584 B per buffer
#define LDS_BYTES (2 * HBUF_S * 2 + 1024)  // 136192 B (h dbuf + i_n coeff table)

#define L2E 1.4426950408889634f
#define LN2 0.6931471805599453f

#define MFMA32(A, B, C) __builtin_amdgcn_mfma_f32_32x32x16_bf16(A, B, C, 0, 0, 0)
#define MFMA16(A, B, C) __builtin_amdgcn_mfma_f32_16x16x32_bf16(A, B, C, 0, 0, 0)

__device__ __forceinline__ unsigned short f2b(float f) {
  unsigned u = __float_as_uint(f);
  u += 0x7FFFu + ((u >> 16) & 1u);     // RNE bf16
  return (unsigned short)(u >> 16);
}

__device__ __forceinline__ float exp2n(float x) { float r; asm("v_exp_f32 %0, -%1" : "=v"(r) : "v"(x)); return r; }
__device__ __forceinline__ float exp2p(float x) { float r; asm("v_exp_f32 %0, %1" : "=v"(r) : "v"(x)); return r; }
__device__ __forceinline__ float rcp_(float x)  { float r; asm("v_rcp_f32 %0, %1" : "=v"(r) : "v"(x)); return r; }
__device__ __forceinline__ float log2_(float x) { float r; asm("v_log_f32 %0, %1" : "=v"(r) : "v"(x)); return r; }
__device__ __forceinline__ unsigned cvtpk(float lo, float hi) {
  unsigned r; asm("v_cvt_pk_bf16_f32 %0, %1, %2" : "=v"(r) : "v"(lo), "v"(hi)); return r;
}

// Pack weights into 32x32x16 MFMA A-fragment order (unfolded, no L2E):
// frag(tr, g, ks): A-row j = g*256 + tr*32 + (lane&31)
// k = ks*16 + (lane>>5)*8 + e (ks<16); ks==16 aug tile: k256=x coeff, k257=bias.
__global__ void gru_prep(const float* __restrict__ Wih, const float* __restrict__ Whh,
                         const float* __restrict__ bih, const float* __restrict__ bhh,
                         const float* __restrict__ Wfc,
                         unsigned short* __restrict__ wfrag,
                         unsigned short* __restrict__ wfc16) {
  int t = blockIdx.x * 256 + threadIdx.x;
  if (t < W32_SHORTS) {
    int e = t & 7, lane = (t >> 3) & 63, frag = t >> 9;
    int ks = frag % 17, g = (frag / 17) & 3, tr = frag / 68;
    int l31 = lane & 31, hh = lane >> 5;
    int k = (ks < 16) ? ks * 16 + hh * 8 + e : 256 + hh * 8 + e;
    float val = 0.f;
    if (g < 3) {
      int j = g * 256 + tr * 32 + l31;
      if (k < 256) val = Whh[j * 256 + k];
      else if (k == 256) val = (g < 2) ? Wih[j] : 0.f;
      else if (k == 257) val = (g < 2) ? (bih[j] + bhh[j]) : bhh[j];
    }
    wfrag[t] = f2b(val);
  } else if (t < W32_SHORTS + WFC_SHORTS) {   // W_fc bf16 [16][256] row-major
    int t2 = t - W32_SHORTS;
    wfc16[t2] = f2b(Wfc[t2]);
  }
}

__global__ void x_transpose(const int* __restrict__ x, int* __restrict__ xT) {
  __shared__ int tile[32][33];
  int l0 = blockIdx.x * 32, b0 = blockIdx.y * 32;
  for (int r = threadIdx.y; r < 32; r += 8)
    tile[r][threadIdx.x] = x[(b0 + r) * LSEQ + l0 + threadIdx.x];
  __syncthreads();
  for (int r = threadIdx.y; r < 32; r += 8)
    xT[(l0 + r) * BATCH + b0 + threadIdx.x] = tile[threadIdx.x][r];
}

template <int XT>
__global__ __attribute__((amdgpu_waves_per_eu(2, 2))) __launch_bounds__(512)
void gru_main(const int* __restrict__ x, const int* __restrict__ xTr,
              const unsigned short* __restrict__ wfrag,
              const unsigned short* __restrict__ wfc16,
              const float* __restrict__ Wih, const float* __restrict__ bih,
              const float* __restrict__ bfc, float* __restrict__ out) {
  extern __shared__ unsigned short sm[];
  unsigned short* h0 = sm;
  unsigned short* h1 = sm + HBUF_S;
  unsigned* wl_in = (unsigned*)(sm + 2 * HBUF_S);   // [8 tr][32 crow] (w|b) packed

  const int tid = threadIdx.x;
  const int lane = tid & 63;
  const int wv = tid >> 6;       // wave 0..7 = j-triple index tr
  const int tr = wv;
  const int l31 = lane & 31;     // batch col within 32-group
  const int hh = lane >> 5;      // k-half
  const int q = lane >> 4;       // FC 16x16 coords
  const int b = lane & 15;
  const int bbase = blockIdx.x * 128;

  { // zero h0 (h1 fully written in step 0 before any read)
    unsigned int* p = (unsigned int*)h0;
#pragma unroll
    for (int r = 0; r < 33; ++r) p[tid + r * 512] = 0u;
  }
  // i_n coefficient table: crow-major per triple, packed (bf16 w | bf16 b)
  if (tid < 256) {
    int j = 512 + tid;           // tid = tr*32 + crow
    wl_in[tid] = (unsigned)f2b(Wih[j]) | ((unsigned)f2b(bih[j]) << 16);
  }

  float bfc4[4];
#pragma unroll
  for (int r = 0; r < 4; ++r) bfc4[r] = bfc[q * 4 + r];

  const f32x16 z16 = {0, 0, 0, 0, 0, 0, 0, 0, 0, 0, 0, 0, 0, 0, 0, 0};

  float lp = 0.f;
  __syncthreads();

#pragma unroll 1
  for (int i = 0; i < LSEQ; ++i) {
    const unsigned short* rdb = (i & 1) ? h1 : h0;   // h_{i-1}
    unsigned short* wrb = (i & 1) ? h0 : h1;         // h_i

    // launder pointers: keep per-step loads from being hoisted across steps
    unsigned long wfu = (unsigned long)wfrag;
    asm volatile("" : "+s"(wfu));
    const unsigned short* wfp = (const unsigned short*)wfu;
    unsigned long wcu = (unsigned long)wfc16;
    asm volatile("" : "+s"(wcu));
    const unsigned short* wc = (const unsigned short*)wcu;

    const unsigned short* fR = wfp + ((tr * 4 + 0) * 17) * 512 + lane * 8;
    const unsigned short* fZ = wfp + ((tr * 4 + 1) * 17) * 512 + lane * 8;
    const unsigned short* fH = wfp + ((tr * 4 + 2) * 17) * 512 + lane * 8;

    // x inputs (x_in = x[:, i-1], 0 at i==0); values 0..15 exact in bf16
    float xin4[4];
    unsigned xlo[4];
#pragma unroll
    for (int bg = 0; bg < 4; ++bg) {
      float xv;
      if (XT) xv = (i > 0) ? (float)xTr[(i - 1) * BATCH + bbase + bg * 32 + l31] : 0.f;
      else    xv = (i > 0) ? (float)x[(bbase + bg * 32 + l31) * LSEQ + i - 1] : 0.f;
      xin4[bg] = xv;
      xlo[bg] = (hh == 0) ? ((__float_as_uint(xv) >> 16) | 0x3F800000u) : 0u;
    }

    // ---- aug-first: initialize 12 accumulators with gi + bias (C = 0) ----
    s16x8 ar = *(const s16x8*)(fR + 16 * 512);
    s16x8 az = *(const s16x8*)(fZ + 16 * 512);
    s16x8 ah = *(const s16x8*)(fH + 16 * 512);
    f32x16 aRc[4], aZc[4], aHc[4];
#pragma unroll
    for (int bg = 0; bg < 4; ++bg) {
      union { unsigned u[4]; s16x8 v; } xf;
      xf.u[0] = xlo[bg]; xf.u[1] = xf.u[2] = xf.u[3] = 0u;
      aRc[bg] = MFMA32(ar, xf.v, z16);
      aZc[bg] = MFMA32(az, xf.v, z16);
      aHc[bg] = MFMA32(ah, xf.v, z16);
    }

    // single LDS base; all B-frag offsets are compile-time immediates
    const unsigned short* rbB = rdb + l31 * HROW + 8 * hh;

    // ---- K loop: weights read ONCE, h B-frags read ONCE per wave ----
    s16x8 cr = *(const s16x8*)(fR);
    s16x8 cz = *(const s16x8*)(fZ);
    s16x8 ch = *(const s16x8*)(fH);
#pragma unroll
    for (int ks = 0; ks < 16; ++ks) {
      s16x8 nr, nz, nh;
      if (ks < 15) {   // depth-1 prefetch
        nr = *(const s16x8*)(fR + (ks + 1) * 512);
        nz = *(const s16x8*)(fZ + (ks + 1) * 512);
        nh = *(const s16x8*)(fH + (ks + 1) * 512);
      }
#pragma unroll
      for (int bg = 0; bg < 4; ++bg) {
        const s16x8 hb = *(const s16x8*)&rbB[bg * 32 * HROW + ks * 16];
        aRc[bg] = MFMA32(cr, hb, aRc[bg]);
        aZc[bg] = MFMA32(cz, hb, aZc[bg]);
        aHc[bg] = MFMA32(ch, hb, aHc[bg]);
      }
      if (ks < 15) { cr = nr; cz = nz; ch = nh; }
    }

    // ---- gate epilogue + direct h write ----
    const unsigned short* rbE = rdb + l31 * HROW + tr * 32 + 4 * hh;
    unsigned short* wbE = wrb + l31 * HROW + tr * 32 + 4 * hh;
    const unsigned* wlt = wl_in + tr * 32 + 4 * hh;
#pragma unroll
    for (int bg = 0; bg < 4; ++bg) {
      const float xv = xin4[bg];
#pragma unroll
      for (int rq = 0; rq < 4; ++rq) {
        const uint2 hp = *(const uint2*)&rbE[bg * 32 * HROW + 8 * rq];
        const float hpv[4] = {
            __uint_as_float(hp.x << 16), __uint_as_float(hp.x & 0xFFFF0000u),
            __uint_as_float(hp.y << 16), __uint_as_float(hp.y & 0xFFFF0000u)};
        float hv[4];
#pragma unroll
        for (int e2 = 0; e2 < 4; ++e2) {
          const int idx = rq * 4 + e2;
          const unsigned u = wlt[8 * rq + e2];
          const float inr = fmaf(xv, __uint_as_float(u << 16),
                                 __uint_as_float(u & 0xFFFF0000u));
          float rr = rcp_(1.f + exp2n(L2E * aRc[bg][idx]));   // sigmoid
          float zz = rcp_(1.f + exp2n(L2E * aZc[bg][idx]));
          float y  = fmaf(rr, aHc[bg][idx], inr);             // i_n + r*h_n
          float uu = rcp_(1.f + exp2p((2.f * L2E) * y));
          float nn = fmaf(-2.f, uu, 1.f);                     // tanh
          hv[e2] = fmaf(zz, hpv[e2] - nn, nn);                // (1-z)*n + z*h
        }
        *(uint2*)&wbE[bg * 32 * HROW + 8 * rq] =
            make_uint2(cvtpk(hv[0], hv[1]), cvtpk(hv[2], hv[3]));
      }
    }

    __syncthreads();   // h_i fully visible; only barrier per step

    { // FC + log_softmax + gather; wave wv handles batch tile bt == wv
      const int lrow = wv * 16 + b;
      const int grow = bbase + lrow;
      f32x4 fa = {bfc4[0], bfc4[1], bfc4[2], bfc4[3]};
      const unsigned short* hbb = wrb + lrow * HROW + 8 * q;
      const unsigned short* wcb = wc + b * 256 + q * 8;
#pragma unroll
      for (int ks = 0; ks < 8; ++ks) {
        s16x8 wfcf = *(const s16x8*)(wcb + 32 * ks);
        s16x8 hb = *(const s16x8*)(hbb + 32 * ks);
        fa = MFMA16(wfcf, hb, fa);
      }
      int tgt = XT ? xTr[i * BATCH + grow] : x[grow * LSEQ + i];
      float l0 = fa[0], l1 = fa[1], l2 = fa[2], l3 = fa[3];
      float mx = fmaxf(fmaxf(l0, l1), fmaxf(l2, l3));
      mx = fmaxf(mx, __shfl_xor(mx, 16));
      mx = fmaxf(mx, __shfl_xor(mx, 32));
      float se = exp2p(L2E * (l0 - mx)) + exp2p(L2E * (l1 - mx)) +
                 exp2p(L2E * (l2 - mx)) + exp2p(L2E * (l3 - mx));
      se += __shfl_xor(se, 16);
      se += __shfl_xor(se, 32);
      float v01 = (tgt & 1) ? l1 : l0;
      float v23 = (tgt & 1) ? l3 : l2;
      float vs = (tgt & 2) ? v23 : v01;
      float contrib = (q == (tgt >> 2)) ? vs : 0.f;
      contrib += __shfl_xor(contrib, 16);
      contrib += __shfl_xor(contrib, 32);
      lp += contrib - mx - LN2 * log2_(se);
    }
  }

  if (q == 0) out[bbase + wv * 16 + b] = lp;
}

extern "C" void kernel_launch(void* const* d_in, const int* in_sizes, int n_in,
                              void* d_out, int out_size, void* d_ws, size_t ws_size,
                              hipStream_t stream) {
  (void)in_sizes; (void)n_in; (void)out_size;
  const int*   x   = (const int*)d_in[0];
  const float* Wih = (const float*)d_in[1];
  const float* Whh = (const float*)d_in[2];
  const float* bih = (const float*)d_in[3];
  const float* bhh = (const float*)d_in[4];
  const float* Wfc = (const float*)d_in[5];
  const float* bfc = (const float*)d_in[6];
  float* out = (float*)d_out;

  unsigned short* wfrag = (unsigned short*)d_ws;
  unsigned short* wfc16 = wfrag + W32_SHORTS;
  int* xT = (int*)((char*)d_ws + XT_OFF_BYTES);

  gru_prep<<<dim3((W32_SHORTS + WFC_SHORTS) / 256), dim3(256), 0, stream>>>(
      Wih, Whh, bih, bhh, Wfc, wfrag, wfc16);

  if (ws_size >= (size_t)WS_NEED_XT) {
    x_transpose<<<dim3(LSEQ / 32, BATCH / 32), dim3(32, 8), 0, stream>>>(x, xT);
    hipFuncSetAttribute((const void*)gru_main<1>,
                        hipFuncAttributeMaxDynamicSharedMemorySize, LDS_BYTES);
    gru_main<1><<<dim3(256), dim3(512), LDS_BYTES, stream>>>(x, xT, wfrag, wfc16,
                                                             Wih, bih, bfc, out);
  } else {
    hipFuncSetAttribute((const void*)gru_main<0>,
                        hipFuncAttributeMaxDynamicSharedMemorySize, LDS_BYTES);
    gru_main<0><<<dim3(256), dim3(512), LDS_BYTES, stream>>>(x, x, wfrag, wfc16,
                                                             Wih, bih, bfc, out);
  }
}